// Round 5
// baseline (1064.412 us; speedup 1.0000x reference)
//
#include <hip/hip_runtime.h>
#include <hip/hip_fp16.h>

// N=1024, F=22, T=1000, H=64, gates 4H=256
// R15: heavy/light wave fusion. R14 post-mortem: MfmaUtil is a SUBSET of
// VALUBusy (MFMA are VALU insts) -> non-MFMA VALU is only ~100cy/tick and the
// tick is ~800cy STALL (chain latency, ds_read, barrier). Fix without extra
// syncs: merge L1+L2 into one wave. In-order issue means the program order
// [MFMA-L1; read-L2; MFMA-L2; gates-L1; gates-L2] lets gates-L1 VALU and the
// L2 ds_reads issue while MFMA chains are in flight. Same single barrier/tick,
// same ring-8 slot math as R12/R13 (re-audited; only executors changed).
//   waves 0-3 (heavy): L1(t=tau-1) + L2(t=tau-2), 32 MFMA, 2 gate sets
//   waves 4-7 (light): L0(t=tau) + x-stage(tau+1), 12 MFMA, 1 gate set
// Per SIMD: 1 heavy + 1 light = 44 MFMA (pipe 785cy, unchanged).
// Bias applied as scalar add after sel4 (frees 24 VGPR; heavy carries 2
// layers' weight frags ~128 VGPR and must fit 2 waves/SIMD <= 256).
#define TT 1000
#define FF 22
#define HH 64
#define BB 4
#define NBLK 256
#define S0 112
#define S1 144
#define SL0 (4 * S0)
#define SL1 (4 * S1)

typedef _Float16 half8 __attribute__((ext_vector_type(8)));
typedef float float4v __attribute__((ext_vector_type(4)));

__device__ __forceinline__ float sel4(const float4v a, int q) {
    float lo = (q & 2) ? a[2] : a[0];
    float hi = (q & 2) ? a[3] : a[1];
    return (q & 1) ? hi : lo;
}

// Fused LSTM gate math: 5 exp + 2 rcp (R13, verified absmax 2.44e-4).
__device__ __forceinline__ float gate_fused(const float z[4], float& c) {
    float e0 = __expf(-z[0]);
    float e1 = __expf(-z[1]);
    float e2 = __expf(2.0f * z[2]);
    float d1 = 1.0f + e1;
    float d2 = (1.0f + e0) * (1.0f + e2);
    float r  = __builtin_amdgcn_rcpf(d1 * d2);
    float f  = d2 * r;
    float ig = (e2 - 1.0f) * (d1 * r);
    float cc = __builtin_fmaf(f, c, ig);
    c = cc;
    float e3 = __expf(-z[3]);
    float e4 = __expf(2.0f * cc);
    float r2 = __builtin_amdgcn_rcpf((1.0f + e3) * (1.0f + e4));
    return (e4 - 1.0f) * r2;
}

// tick boundary: LDS release + barrier + compiler fence
#define SYNC() do { asm volatile("s_waitcnt lgkmcnt(0)" ::: "memory"); \
                    __builtin_amdgcn_s_barrier(); \
                    asm volatile("" ::: "memory"); } while (0)

extern "C" __global__ void __launch_bounds__(512, 2)
lstm_fused(const float* __restrict__ x,
           const float* __restrict__ Wih0, const float* __restrict__ Whh0,
           const float* __restrict__ bih0, const float* __restrict__ bhh0,
           const float* __restrict__ Wih1, const float* __restrict__ Whh1,
           const float* __restrict__ bih1, const float* __restrict__ bhh1,
           const float* __restrict__ Wih2, const float* __restrict__ Whh2,
           const float* __restrict__ bih2, const float* __restrict__ bhh2,
           const float* __restrict__ w0, const float* __restrict__ b0,
           const float* __restrict__ w1, const float* __restrict__ b1,
           const float* __restrict__ w2, const float* __restrict__ b2,
           const float* __restrict__ w3, const float* __restrict__ b3,
           const float* __restrict__ g0, const float* __restrict__ be0,
           const float* __restrict__ m0, const float* __restrict__ v0,
           const float* __restrict__ g1, const float* __restrict__ be1,
           const float* __restrict__ m1, const float* __restrict__ v1,
           const float* __restrict__ g2, const float* __restrict__ be2,
           const float* __restrict__ m2, const float* __restrict__ v2,
           float* __restrict__ out)
{
    __shared__ __align__(16) _Float16 in0[8 * SL0];
    __shared__ __align__(16) _Float16 in1[8 * SL1];
    __shared__ __align__(16) _Float16 in2[8 * SL1];
    __shared__ float fcA[BB * 64];
    __shared__ float fcB[BB * 64];
    __shared__ float fcW[54 * 65];
    __shared__ float fcP[5 * 64];

    const int tid   = threadIdx.x;
    const int wv    = tid >> 6;          // 0..7
    const bool heavy = (wv < 4);         // 0-3: L1+L2, 4-7: L0+x
    const int cset  = heavy ? wv : (wv - 4);
    const int l     = tid & 63;
    const int q     = l >> 4;
    const int l15   = l & 15;
    const int u     = 16 * cset + l15;
    const int b     = q;
    const int n0    = blockIdx.x * BB;

    for (int i = tid; i < 8 * SL0; i += 512) in0[i] = (_Float16)0.0f;
    for (int i = tid; i < 8 * SL1; i += 512) in1[i] = (_Float16)0.0f;
    for (int i = tid; i < 8 * SL1; i += 512) in2[i] = (_Float16)0.0f;

    // ---- weight B-fragments ----
    half8 wf1[4][4], wf2[4][4];          // heavy: L1, L2
    half8 wf0[4][3];                     // light: L0
    float bv1[4], bv2[4], bv0[4];
    if (heavy) {
#pragma unroll
        for (int g = 0; g < 4; ++g) {
            const int row = 64 * g + u;
#pragma unroll
            for (int kt = 0; kt < 4; ++kt) {
                half8 h{}, h2{};
#pragma unroll
                for (int j = 0; j < 8; ++j) {
                    const int k = 32 * kt + 8 * q + j;
                    h[j]  = (_Float16)((k < 64) ? Wih1[row * HH + k] : Whh1[row * HH + (k - 64)]);
                    h2[j] = (_Float16)((k < 64) ? Wih2[row * HH + k] : Whh2[row * HH + (k - 64)]);
                }
                wf1[g][kt] = h;
                wf2[g][kt] = h2;
            }
            bv1[g] = bih1[row] + bhh1[row];
            bv2[g] = bih2[row] + bhh2[row];
        }
    } else {
#pragma unroll
        for (int g = 0; g < 4; ++g) {
            const int row = 64 * g + u;
#pragma unroll
            for (int kt = 0; kt < 3; ++kt) {
                half8 h{};
#pragma unroll
                for (int j = 0; j < 8; ++j) {
                    const int k = 32 * kt + 8 * q + j;
                    float val = 0.0f;
                    if (k < 32) { if (k < FF) val = Wih0[row * FF + k]; }
                    else        { val = Whh0[row * HH + (k - 32)]; }
                    h[j] = (_Float16)val;
                }
                wf0[g][kt] = h;
            }
            bv0[g] = bih0[row] + bhh0[row];
        }
    }

    // ---- x staging: light wave lw stages batch lw, lanes 0..21 = feature ----
    const bool xok = (!heavy) && (l < FF);
    const int  xb  = cset;               // batch = light wave index
    const float* xp = x + ((size_t)(n0 + xb) * FF + l) * TT;

    __syncthreads();                     // zero-init complete

    // pre-stage x(0) into slot 0; ordered by first in-loop SYNC
    if (xok) in0[0 * SL0 + xb * S0 + l] = (_Float16)xp[0];
    float xA = xok ? xp[1] : 0.f;        // value to write at tau=0 (timestep 1)
    float xB = xok ? xp[2] : 0.f;        // depth-2 prefetch

    const int arow = heavy ? ((l15 & 3) * S1 + q * 8) : ((l15 & 3) * S0 + q * 8);
    float c1 = 0.f, c2 = 0.f, c0 = 0.f;
    const float4v zz = {0.f, 0.f, 0.f, 0.f};

    // ============ main loop: 126*8 = 1008 ticks, 1 barrier each ============
    for (int k = 0; k < 126; ++k) {
#pragma unroll
        for (int s = 0; s < 8; ++s) {
            const int tau = 8 * k + s;
            SYNC();

            if (heavy) {
                const bool do1 = (tau >= 1) && (tau <= TT);      // L1 t=tau-1
                const bool do2 = (tau >= 2) && (tau <= TT + 1);  // L2 t=tau-2
                float4v A1[4], A2[4];
                if (do1) {               // L1 MFMA: in1 slot (tau-1)&7
                    const _Float16* rd = in1 + ((s + 7) & 7) * SL1;
                    half8 a0 = *(const half8*)(rd + arow);
                    half8 a1 = *(const half8*)(rd + arow + 32);
                    half8 a2 = *(const half8*)(rd + arow + 64);
                    half8 a3 = *(const half8*)(rd + arow + 96);
#pragma unroll
                    for (int g = 0; g < 4; ++g)
                        A1[g] = __builtin_amdgcn_mfma_f32_16x16x32_f16(a0, wf1[g][0], zz, 0, 0, 0);
#pragma unroll
                    for (int g = 0; g < 4; ++g)
                        A1[g] = __builtin_amdgcn_mfma_f32_16x16x32_f16(a1, wf1[g][1], A1[g], 0, 0, 0);
#pragma unroll
                    for (int g = 0; g < 4; ++g)
                        A1[g] = __builtin_amdgcn_mfma_f32_16x16x32_f16(a2, wf1[g][2], A1[g], 0, 0, 0);
#pragma unroll
                    for (int g = 0; g < 4; ++g)
                        A1[g] = __builtin_amdgcn_mfma_f32_16x16x32_f16(a3, wf1[g][3], A1[g], 0, 0, 0);
                }
                if (do2) {               // L2 MFMA: in2 slot (tau-2)&7
                    const _Float16* rd = in2 + ((s + 6) & 7) * SL1;
                    half8 a0 = *(const half8*)(rd + arow);
                    half8 a1 = *(const half8*)(rd + arow + 32);
                    half8 a2 = *(const half8*)(rd + arow + 64);
                    half8 a3 = *(const half8*)(rd + arow + 96);
#pragma unroll
                    for (int g = 0; g < 4; ++g)
                        A2[g] = __builtin_amdgcn_mfma_f32_16x16x32_f16(a0, wf2[g][0], zz, 0, 0, 0);
#pragma unroll
                    for (int g = 0; g < 4; ++g)
                        A2[g] = __builtin_amdgcn_mfma_f32_16x16x32_f16(a1, wf2[g][1], A2[g], 0, 0, 0);
#pragma unroll
                    for (int g = 0; g < 4; ++g)
                        A2[g] = __builtin_amdgcn_mfma_f32_16x16x32_f16(a2, wf2[g][2], A2[g], 0, 0, 0);
#pragma unroll
                    for (int g = 0; g < 4; ++g)
                        A2[g] = __builtin_amdgcn_mfma_f32_16x16x32_f16(a3, wf2[g][3], A2[g], 0, 0, 0);
                }
                if (do1) {               // L1 gates — issues under L2 MFMA chains
                    float z[4];
#pragma unroll
                    for (int g = 0; g < 4; ++g) z[g] = sel4(A1[g], q) + bv1[g];
                    float h = gate_fused(z, c1);
                    _Float16 hf = (_Float16)h;
                    in1[s * SL1 + b * S1 + 64 + u]            = hf; // rec -> slot tau&7
                    in2[((s + 7) & 7) * SL1 + b * S1 + u]     = hf; // fwd -> slot (tau-1)&7
                }
                if (do2) {               // L2 gates
                    float z[4];
#pragma unroll
                    for (int g = 0; g < 4; ++g) z[g] = sel4(A2[g], q) + bv2[g];
                    float h = gate_fused(z, c2);
                    if (tau != TT + 1) {
                        in2[((s + 7) & 7) * SL1 + b * S1 + 64 + u] = (_Float16)h; // rec
                    } else {
                        fcA[b * 64 + u] = h;              // final h2(999), fp32
                    }
                }
            } else {
                // ---- x stage: write x(tau+1) into slot (tau+1)&7 ----
                if (tau <= TT - 2) {
                    if (xok) in0[((s + 1) & 7) * SL0 + xb * S0 + l] = (_Float16)xA;
                    xA = xB;
                    if (xok) {
                        int tn = tau + 3; if (tn > TT - 1) tn = TT - 1;
                        xB = xp[tn];
                    }
                }
                // ---- L0: t = tau ----
                if (tau <= TT - 1) {
                    const _Float16* rd = in0 + s * SL0;
                    half8 a0 = *(const half8*)(rd + arow);
                    half8 a1 = *(const half8*)(rd + arow + 32);
                    half8 a2 = *(const half8*)(rd + arow + 64);
                    float4v A0[4];
#pragma unroll
                    for (int g = 0; g < 4; ++g)
                        A0[g] = __builtin_amdgcn_mfma_f32_16x16x32_f16(a0, wf0[g][0], zz, 0, 0, 0);
#pragma unroll
                    for (int g = 0; g < 4; ++g)
                        A0[g] = __builtin_amdgcn_mfma_f32_16x16x32_f16(a1, wf0[g][1], A0[g], 0, 0, 0);
#pragma unroll
                    for (int g = 0; g < 4; ++g)
                        A0[g] = __builtin_amdgcn_mfma_f32_16x16x32_f16(a2, wf0[g][2], A0[g], 0, 0, 0);
                    float z[4];
#pragma unroll
                    for (int g = 0; g < 4; ++g) z[g] = sel4(A0[g], q) + bv0[g];
                    float h = gate_fused(z, c0);
                    _Float16 hf = (_Float16)h;
                    in0[((s + 1) & 7) * SL0 + b * S0 + 32 + u] = hf; // rec -> slot tau+1
                    in1[s * SL1 + b * S1 + u]                  = hf; // fwd -> slot tau
                }
            }
        }
    }

    __syncthreads();

    // ================= FC head (fp32) =================
    for (int i = tid; i < 54 * 64; i += 512) fcW[(i >> 6) * 65 + (i & 63)] = w0[i];
    for (int i = tid; i < 54; i += 512) {
        fcP[i] = b0[i]; fcP[64 + i] = g0[i]; fcP[128 + i] = be0[i];
        fcP[192 + i] = m0[i]; fcP[256 + i] = v0[i];
    }
    __syncthreads();
    for (int idx = tid; idx < BB * 54; idx += 512) {
        const int bb = idx / 54, j = idx - bb * 54;
        float s = fcP[j];
        for (int k = 0; k < 64; ++k) s += fcW[j * 65 + k] * fcA[bb * 64 + k];
        s = (s - fcP[192 + j]) * rsqrtf(fcP[256 + j] + 1e-5f) * fcP[64 + j] + fcP[128 + j];
        fcB[bb * 64 + j] = fmaxf(s, 0.0f);
    }
    __syncthreads();

    for (int i = tid; i < 44 * 54; i += 512) fcW[(i / 54) * 55 + (i % 54)] = w1[i];
    for (int i = tid; i < 44; i += 512) {
        fcP[i] = b1[i]; fcP[64 + i] = g1[i]; fcP[128 + i] = be1[i];
        fcP[192 + i] = m1[i]; fcP[256 + i] = v1[i];
    }
    __syncthreads();
    for (int idx = tid; idx < BB * 44; idx += 512) {
        const int bb = idx / 44, j = idx - bb * 44;
        float s = fcP[j];
        for (int k = 0; k < 54; ++k) s += fcW[j * 55 + k] * fcB[bb * 64 + k];
        s = (s - fcP[192 + j]) * rsqrtf(fcP[256 + j] + 1e-5f) * fcP[64 + j] + fcP[128 + j];
        fcA[bb * 64 + j] = fmaxf(s, 0.0f);
    }
    __syncthreads();

    for (int i = tid; i < 24 * 44; i += 512) fcW[(i / 44) * 45 + (i % 44)] = w2[i];
    for (int i = tid; i < 24; i += 512) {
        fcP[i] = b2[i]; fcP[64 + i] = g2[i]; fcP[128 + i] = be2[i];
        fcP[192 + i] = m2[i]; fcP[256 + i] = v2[i];
    }
    __syncthreads();
    for (int idx = tid; idx < BB * 24; idx += 512) {
        const int bb = idx / 24, j = idx - bb * 24;
        float s = fcP[j];
        for (int k = 0; k < 44; ++k) s += fcW[j * 45 + k] * fcA[bb * 64 + k];
        s = (s - fcP[192 + j]) * rsqrtf(fcP[256 + j] + 1e-5f) * fcP[64 + j] + fcP[128 + j];
        fcB[bb * 64 + j] = fmaxf(s, 0.0f);
    }
    __syncthreads();

    for (int i = tid; i < 4 * 24; i += 512) fcW[(i / 24) * 25 + (i % 24)] = w3[i];
    for (int i = tid; i < 4; i += 512) fcP[i] = b3[i];
    __syncthreads();
    for (int idx = tid; idx < BB * 4; idx += 512) {
        const int bb = idx / 4, j = idx - bb * 4;
        float s = fcP[j];
        for (int k = 0; k < 24; ++k) s += fcW[j * 25 + k] * fcB[bb * 64 + k];
        out[(size_t)(n0 + bb) * 4 + j] = s;
    }
}

extern "C" void kernel_launch(void* const* d_in, const int* in_sizes, int n_in,
                              void* d_out, int out_size, void* d_ws, size_t ws_size,
                              hipStream_t stream) {
    const float* p[33];
    for (int i = 0; i < 33; ++i) p[i] = (const float*)d_in[i];
    lstm_fused<<<NBLK, 512, 0, stream>>>(
        p[0],
        p[1], p[2], p[3], p[4],
        p[5], p[6], p[7], p[8],
        p[9], p[10], p[11], p[12],
        p[13], p[14], p[15], p[16], p[17], p[18], p[19], p[20],
        p[21], p[22], p[23], p[24],
        p[25], p[26], p[27], p[28],
        p[29], p[30], p[31], p[32],
        (float*)d_out);
}

// Round 6
// 877.547 us; speedup vs baseline: 1.2129x; 1.2129x over previous
//
#include <hip/hip_runtime.h>
#include <hip/hip_fp16.h>

// N=1024, F=22, T=1000, H=64, gates 4H=256
// R16: R13 base (1 barrier/tick lockstep, 703us) + PRE-READ HOISTING.
// Model from R13/R15 counters: per-SIMD MFMA issue floor = 44 x 19.4 = 854cy;
// R13 tick 1688cy = 854 busy + ~830 ALIGNED idle (post-barrier ds_read latency
// + gate/drain tail, synchronized across waves by the barrier).
// Fix: lags L0 t=tau, L1 t=tau-2, L2 t=tau-4 -> each layer's FWD operands are
// >=2 barriers old -> ds_read them in the PREVIOUS tick (hidden under gates)
// and carry in regs across the barrier. At barrier+0 each wave issues 8 fwd
// MFMAs immediately (24 ready/SIMD ~ 466cy) under which the 1-tick-old REC
// reads complete. Single barrier kept; no setprio; no phase split.
// Also: stager waves folded into L0 (lead-2 x writes, depth-2 reg prefetch)
// -> 12 waves = exactly 3/SIMD, balanced 44 MFMA/SIMD.
// Slot audit (ring 8, s = tau&7): writes at tick tau:
//   L0: rec h0(tau)->in0 slot(s+1) c32..95 | fwd h0(tau)->in1 slot s c0..63
//       x(tau+2)->in0 slot(s+2) c0..21
//   L1(t=tau-2): rec->in1 slot(s+7) c64..127 | fwd->in2 slot(s+6) c0..63
//   L2(t=tau-4): rec->in2 slot(s+5) c64..127
// reads at tick tau: L0 rec slot s c32..95 (post-bar), x pre-read slot(s+1);
//   L1 rec slot(s+6) c64..127 (post), fwd pre-read slot(s+7) c0..63;
//   L2 rec slot(s+4) c64..127 (post), fwd pre-read slot(s+5) c0..63.
// All edges >=1 barrier; concurrent same-slot writes col-disjoint; overwrite
// distance >=7 ticks; guards: L0 tau<=999, L1 2<=tau<=1001, L2 4<=tau<=1003.
// 768 thr = 12 waves: 0-3 L2, 4-7 L1, 8-11 L0(+x-stage lanes 0..21).
#define TT 1000
#define FF 22
#define HH 64
#define BB 4
#define NBLK 256
#define S0 112
#define S1 144
#define SL0 (4 * S0)
#define SL1 (4 * S1)

typedef _Float16 half8 __attribute__((ext_vector_type(8)));
typedef float float4v __attribute__((ext_vector_type(4)));

__device__ __forceinline__ float sel4(const float4v a, int q) {
    float lo = (q & 2) ? a[2] : a[0];
    float hi = (q & 2) ? a[3] : a[1];
    return (q & 1) ? hi : lo;
}

// Fused LSTM gate math: 5 exp + 2 rcp (R13, verified absmax 2.44e-4).
__device__ __forceinline__ float gate_fused(const float z[4], float& c) {
    float e0 = __expf(-z[0]);
    float e1 = __expf(-z[1]);
    float e2 = __expf(2.0f * z[2]);
    float d1 = 1.0f + e1;
    float d2 = (1.0f + e0) * (1.0f + e2);
    float r  = __builtin_amdgcn_rcpf(d1 * d2);
    float f  = d2 * r;
    float ig = (e2 - 1.0f) * (d1 * r);
    float cc = __builtin_fmaf(f, c, ig);
    c = cc;
    float e3 = __expf(-z[3]);
    float e4 = __expf(2.0f * cc);
    float r2 = __builtin_amdgcn_rcpf((1.0f + e3) * (1.0f + e4));
    return (e4 - 1.0f) * r2;
}

// tick boundary: LDS release + barrier + compiler fence
#define SYNC() do { asm volatile("s_waitcnt lgkmcnt(0)" ::: "memory"); \
                    __builtin_amdgcn_s_barrier(); \
                    asm volatile("" ::: "memory"); } while (0)

extern "C" __global__ void __launch_bounds__(768, 1)
lstm_fused(const float* __restrict__ x,
           const float* __restrict__ Wih0, const float* __restrict__ Whh0,
           const float* __restrict__ bih0, const float* __restrict__ bhh0,
           const float* __restrict__ Wih1, const float* __restrict__ Whh1,
           const float* __restrict__ bih1, const float* __restrict__ bhh1,
           const float* __restrict__ Wih2, const float* __restrict__ Whh2,
           const float* __restrict__ bih2, const float* __restrict__ bhh2,
           const float* __restrict__ w0, const float* __restrict__ b0,
           const float* __restrict__ w1, const float* __restrict__ b1,
           const float* __restrict__ w2, const float* __restrict__ b2,
           const float* __restrict__ w3, const float* __restrict__ b3,
           const float* __restrict__ g0, const float* __restrict__ be0,
           const float* __restrict__ m0, const float* __restrict__ v0,
           const float* __restrict__ g1, const float* __restrict__ be1,
           const float* __restrict__ m1, const float* __restrict__ v1,
           const float* __restrict__ g2, const float* __restrict__ be2,
           const float* __restrict__ m2, const float* __restrict__ v2,
           float* __restrict__ out)
{
    __shared__ __align__(16) _Float16 in0[8 * SL0];
    __shared__ __align__(16) _Float16 in1[8 * SL1];
    __shared__ __align__(16) _Float16 in2[8 * SL1];
    __shared__ float fcA[BB * 64];
    __shared__ float fcB[BB * 64];
    __shared__ float fcW[54 * 65];
    __shared__ float fcP[5 * 64];

    const int tid  = threadIdx.x;
    const int wv   = tid >> 6;      // 0..11
    const int role = wv >> 2;       // 0=L2, 1=L1, 2=L0(+stage)
    const int w4   = wv & 3;
    const int l    = tid & 63;
    const int q    = l >> 4;
    const int l15  = l & 15;
    const int u    = 16 * w4 + l15;
    const int b    = q;
    const int n0   = blockIdx.x * BB;

    for (int i = tid; i < 8 * SL0; i += 768) in0[i] = (_Float16)0.0f;
    for (int i = tid; i < 8 * SL1; i += 768) in1[i] = (_Float16)0.0f;
    for (int i = tid; i < 8 * SL1; i += 768) in2[i] = (_Float16)0.0f;

    // ---- weight B-fragments: one unit-slice per wave ----
    half8 wf[4][4];
    float bv[4];
    if (role == 2) {                 // layer 0 (3 kt used)
#pragma unroll
        for (int g = 0; g < 4; ++g) {
            const int row = 64 * g + u;
#pragma unroll
            for (int kt = 0; kt < 3; ++kt) {
                half8 h{};
#pragma unroll
                for (int j = 0; j < 8; ++j) {
                    const int k = 32 * kt + 8 * q + j;
                    float val = 0.0f;
                    if (k < 32) { if (k < FF) val = Wih0[row * FF + k]; }
                    else        { val = Whh0[row * HH + (k - 32)]; }
                    h[j] = (_Float16)val;
                }
                wf[g][kt] = h;
            }
            wf[g][3] = half8{};
            bv[g] = bih0[row] + bhh0[row];
        }
    } else {                          // 0 -> layer 2, 1 -> layer 1
        const float* Wih = role ? Wih1 : Wih2;
        const float* Whh = role ? Whh1 : Whh2;
        const float* bih = role ? bih1 : bih2;
        const float* bhh = role ? bhh1 : bhh2;
#pragma unroll
        for (int g = 0; g < 4; ++g) {
            const int row = 64 * g + u;
#pragma unroll
            for (int kt = 0; kt < 4; ++kt) {
                half8 h{};
#pragma unroll
                for (int j = 0; j < 8; ++j) {
                    const int k = 32 * kt + 8 * q + j;
                    h[j] = (_Float16)((k < 64) ? Wih[row * HH + k] : Whh[row * HH + (k - 64)]);
                }
                wf[g][kt] = h;
            }
            bv[g] = bih[row] + bhh[row];
        }
    }

    // ---- x staging (folded into L0 waves): lane<22 stages batch w4 ----
    const bool xok = (role == 2) && (l < FF);
    const int  xb  = w4;
    const float* xp = x + ((size_t)(n0 + xb) * FF + l) * TT;

    __syncthreads();                 // zero-init visible

    // pre-stage x(0) -> slot 0, x(1) -> slot 1
    if (xok) {
        in0[0 * SL0 + xb * S0 + l] = (_Float16)xp[0];
        in0[1 * SL0 + xb * S0 + l] = (_Float16)xp[1];
    }
    float xA = xok ? xp[2] : 0.f;    // to write at tick 0 (x(2))
    float xB = xok ? xp[3] : 0.f;    // depth-2 prefetch

    __syncthreads();                 // pre-staged x visible to all L0 waves

    const int arow = (role == 2) ? ((l15 & 3) * S0 + q * 8) : ((l15 & 3) * S1 + q * 8);
    float c = 0.f;
    const float4v zz = {0.f, 0.f, 0.f, 0.f};

    // fwd operands carried across the barrier (pre-read previous tick)
    half8 pre0{}, pre1{};
    if (role == 2) pre0 = *(const half8*)(in0 + arow);   // x(0) zone, slot 0

    // ============ main loop: 126*8 = 1008 ticks, 1 barrier each ============
    for (int k = 0; k < 126; ++k) {
#pragma unroll
        for (int s = 0; s < 8; ++s) {
            const int tau = 8 * k + s;
            SYNC();

            if (role == 2) {         // ===== L0: t = tau =====
                const bool act = (tau <= TT - 1);
                float4v A[4];
                if (act) {
                    const _Float16* rd = in0 + s * SL0;
                    half8 a1 = *(const half8*)(rd + arow + 32);   // rec lo
                    half8 a2 = *(const half8*)(rd + arow + 64);   // rec hi
#pragma unroll
                    for (int g = 0; g < 4; ++g)
                        A[g] = __builtin_amdgcn_mfma_f32_16x16x32_f16(pre0, wf[g][0], zz, 0, 0, 0);
#pragma unroll
                    for (int g = 0; g < 4; ++g)
                        A[g] = __builtin_amdgcn_mfma_f32_16x16x32_f16(a1, wf[g][1], A[g], 0, 0, 0);
#pragma unroll
                    for (int g = 0; g < 4; ++g)
                        A[g] = __builtin_amdgcn_mfma_f32_16x16x32_f16(a2, wf[g][2], A[g], 0, 0, 0);
                }
                // pre-read next tick's x fragment (slot tau+1, written >=1 bar ago)
                pre0 = *(const half8*)(in0 + ((s + 1) & 7) * SL0 + arow);
                if (act) {
                    float z[4];
#pragma unroll
                    for (int g = 0; g < 4; ++g) z[g] = sel4(A[g], q) + bv[g];
                    float h = gate_fused(z, c);
                    _Float16 hf = (_Float16)h;
                    in0[((s + 1) & 7) * SL0 + b * S0 + 32 + u] = hf; // rec -> slot tau+1
                    in1[s * SL1 + b * S1 + u]                  = hf; // fwd -> slot tau
                }
                // x staging: write x(tau+2) (lead 2), prefetch x(tau+4)
                if (xok && tau <= TT - 3)
                    in0[((s + 2) & 7) * SL0 + xb * S0 + l] = (_Float16)xA;
                xA = xB;
                if (xok) {
                    int tn = tau + 4; if (tn > TT - 1) tn = TT - 1;
                    xB = xp[tn];
                }
            } else if (role == 1) {  // ===== L1: t = tau-2 =====
                const bool act = (tau >= 2) && (tau <= TT + 1);
                float4v A[4];
                if (act) {
                    const _Float16* rd = in2 /*dummy*/ , *rr = in1 + ((s + 6) & 7) * SL1;
                    (void)rd;
                    half8 a2 = *(const half8*)(rr + arow + 64);   // rec lo
                    half8 a3 = *(const half8*)(rr + arow + 96);   // rec hi
#pragma unroll
                    for (int g = 0; g < 4; ++g)
                        A[g] = __builtin_amdgcn_mfma_f32_16x16x32_f16(pre0, wf[g][0], zz, 0, 0, 0);
#pragma unroll
                    for (int g = 0; g < 4; ++g)
                        A[g] = __builtin_amdgcn_mfma_f32_16x16x32_f16(pre1, wf[g][1], A[g], 0, 0, 0);
#pragma unroll
                    for (int g = 0; g < 4; ++g)
                        A[g] = __builtin_amdgcn_mfma_f32_16x16x32_f16(a2, wf[g][2], A[g], 0, 0, 0);
#pragma unroll
                    for (int g = 0; g < 4; ++g)
                        A[g] = __builtin_amdgcn_mfma_f32_16x16x32_f16(a3, wf[g][3], A[g], 0, 0, 0);
                }
                // pre-read next tick's fwd fragments: slot (tau-1)&7 c0..63
                {
                    const _Float16* rn = in1 + ((s + 7) & 7) * SL1;
                    pre0 = *(const half8*)(rn + arow);
                    pre1 = *(const half8*)(rn + arow + 32);
                }
                if (act) {
                    float z[4];
#pragma unroll
                    for (int g = 0; g < 4; ++g) z[g] = sel4(A[g], q) + bv[g];
                    float h = gate_fused(z, c);
                    _Float16 hf = (_Float16)h;
                    in1[((s + 7) & 7) * SL1 + b * S1 + 64 + u] = hf; // rec -> slot (tau-1)&7
                    in2[((s + 6) & 7) * SL1 + b * S1 + u]      = hf; // fwd -> slot (tau-2)&7
                }
            } else {                 // ===== L2: t = tau-4 =====
                const bool act = (tau >= 4) && (tau <= TT + 3);
                float4v A[4];
                if (act) {
                    const _Float16* rr = in2 + ((s + 4) & 7) * SL1;
                    half8 a2 = *(const half8*)(rr + arow + 64);   // rec lo
                    half8 a3 = *(const half8*)(rr + arow + 96);   // rec hi
#pragma unroll
                    for (int g = 0; g < 4; ++g)
                        A[g] = __builtin_amdgcn_mfma_f32_16x16x32_f16(pre0, wf[g][0], zz, 0, 0, 0);
#pragma unroll
                    for (int g = 0; g < 4; ++g)
                        A[g] = __builtin_amdgcn_mfma_f32_16x16x32_f16(pre1, wf[g][1], A[g], 0, 0, 0);
#pragma unroll
                    for (int g = 0; g < 4; ++g)
                        A[g] = __builtin_amdgcn_mfma_f32_16x16x32_f16(a2, wf[g][2], A[g], 0, 0, 0);
#pragma unroll
                    for (int g = 0; g < 4; ++g)
                        A[g] = __builtin_amdgcn_mfma_f32_16x16x32_f16(a3, wf[g][3], A[g], 0, 0, 0);
                }
                // pre-read next tick's fwd fragments: slot (tau-3)&7 c0..63
                {
                    const _Float16* rn = in2 + ((s + 5) & 7) * SL1;
                    pre0 = *(const half8*)(rn + arow);
                    pre1 = *(const half8*)(rn + arow + 32);
                }
                if (act) {
                    float z[4];
#pragma unroll
                    for (int g = 0; g < 4; ++g) z[g] = sel4(A[g], q) + bv[g];
                    float h = gate_fused(z, c);
                    if (tau != TT + 3) {
                        in2[((s + 5) & 7) * SL1 + b * S1 + 64 + u] = (_Float16)h; // rec -> slot (tau-3)&7
                    } else {
                        fcA[b * 64 + u] = h;              // final h2(999), fp32
                    }
                }
            }
        }
    }

    __syncthreads();

    // ================= FC head (fp32) =================
    for (int i = tid; i < 54 * 64; i += 768) fcW[(i >> 6) * 65 + (i & 63)] = w0[i];
    for (int i = tid; i < 54; i += 768) {
        fcP[i] = b0[i]; fcP[64 + i] = g0[i]; fcP[128 + i] = be0[i];
        fcP[192 + i] = m0[i]; fcP[256 + i] = v0[i];
    }
    __syncthreads();
    for (int idx = tid; idx < BB * 54; idx += 768) {
        const int bb = idx / 54, j = idx - bb * 54;
        float s = fcP[j];
        for (int k = 0; k < 64; ++k) s += fcW[j * 65 + k] * fcA[bb * 64 + k];
        s = (s - fcP[192 + j]) * rsqrtf(fcP[256 + j] + 1e-5f) * fcP[64 + j] + fcP[128 + j];
        fcB[bb * 64 + j] = fmaxf(s, 0.0f);
    }
    __syncthreads();

    for (int i = tid; i < 44 * 54; i += 768) fcW[(i / 54) * 55 + (i % 54)] = w1[i];
    for (int i = tid; i < 44; i += 768) {
        fcP[i] = b1[i]; fcP[64 + i] = g1[i]; fcP[128 + i] = be1[i];
        fcP[192 + i] = m1[i]; fcP[256 + i] = v1[i];
    }
    __syncthreads();
    for (int idx = tid; idx < BB * 44; idx += 768) {
        const int bb = idx / 44, j = idx - bb * 44;
        float s = fcP[j];
        for (int k = 0; k < 54; ++k) s += fcW[j * 55 + k] * fcB[bb * 64 + k];
        s = (s - fcP[192 + j]) * rsqrtf(fcP[256 + j] + 1e-5f) * fcP[64 + j] + fcP[128 + j];
        fcA[bb * 64 + j] = fmaxf(s, 0.0f);
    }
    __syncthreads();

    for (int i = tid; i < 24 * 44; i += 768) fcW[(i / 44) * 45 + (i % 44)] = w2[i];
    for (int i = tid; i < 24; i += 768) {
        fcP[i] = b2[i]; fcP[64 + i] = g2[i]; fcP[128 + i] = be2[i];
        fcP[192 + i] = m2[i]; fcP[256 + i] = v2[i];
    }
    __syncthreads();
    for (int idx = tid; idx < BB * 24; idx += 768) {
        const int bb = idx / 24, j = idx - bb * 24;
        float s = fcP[j];
        for (int k = 0; k < 44; ++k) s += fcW[j * 45 + k] * fcA[bb * 64 + k];
        s = (s - fcP[192 + j]) * rsqrtf(fcP[256 + j] + 1e-5f) * fcP[64 + j] + fcP[128 + j];
        fcB[bb * 64 + j] = fmaxf(s, 0.0f);
    }
    __syncthreads();

    for (int i = tid; i < 4 * 24; i += 768) fcW[(i / 24) * 25 + (i % 24)] = w3[i];
    for (int i = tid; i < 4; i += 768) fcP[i] = b3[i];
    __syncthreads();
    for (int idx = tid; idx < BB * 4; idx += 768) {
        const int bb = idx / 4, j = idx - bb * 4;
        float s = fcP[j];
        for (int k = 0; k < 24; ++k) s += fcW[j * 25 + k] * fcB[bb * 64 + k];
        out[(size_t)(n0 + bb) * 4 + j] = s;
    }
}

extern "C" void kernel_launch(void* const* d_in, const int* in_sizes, int n_in,
                              void* d_out, int out_size, void* d_ws, size_t ws_size,
                              hipStream_t stream) {
    const float* p[33];
    for (int i = 0; i < 33; ++i) p[i] = (const float*)d_in[i];
    lstm_fused<<<NBLK, 768, 0, stream>>>(
        p[0],
        p[1], p[2], p[3], p[4],
        p[5], p[6], p[7], p[8],
        p[9], p[10], p[11], p[12],
        p[13], p[14], p[15], p[16], p[17], p[18], p[19], p[20],
        p[21], p[22], p[23], p[24],
        p[25], p[26], p[27], p[28],
        p[29], p[30], p[31], p[32],
        (float*)d_out);
}

// Round 7
// 780.871 us; speedup vs baseline: 1.3631x; 1.1238x over previous
//
#include <hip/hip_runtime.h>
#include <hip/hip_fp16.h>

// N=1024, F=22, T=1000, H=64, gates 4H=256
// R17: pre-barrier ISSUE of fwd MFMAs (R16 only pre-READ operands).
// Model: per-SIMD MFMA pipe floor 44x19.4=854cy/tick; tick 1700-1950 because
// the barrier aligns two pipe-idle zones (post-barrier operand reads, gate
// tail). Fix: with lags L0=tau, L1=tau-2, L2=tau-4, each layer's FWD operands
// are >=2 barriers old -> issue the fwd MFMAs for step tau+1 AT TICK tau,
// after gates, before the barrier; acc carries the partial sum across SYNC.
// Post-barrier: rec ds_read + 2-deep rec MFMA chain + gates + writes only
// (24 MFMA/SIMD post, 20 pre -> tail now feeds the matrix pipe).
// vs R16: stager restored to separate waves (12-13), 14 waves total.
// Slot audit (ring 8, s=tau&7), writes at tick tau:
//   ST:  x(tau+2) -> in0 slot(s+2) c0..21
//   L0(t=tau):   rec->in0 slot(s+1) c32..95 | fwd->in1 slot s c0..63
//   L1(t=tau-2): rec->in1 slot(s+7) c64..127 | fwd->in2 slot(s+6) c0..63
//   L2(t=tau-4): rec->in2 slot(s+5) c64..127
// reads at tick tau:
//   L0 cur rec: in0 slot s c32..95 (wr tick tau-1) | L0 pre: in0 slot(s+1)
//     c0..21 (x(tau+1), wr tick tau-1 by ST; same-slot same-tick L0 rec write
//     is c32..95, disjoint)
//   L1 cur rec: in1 slot(s+6) c64..127 (wr tau-1) | L1 pre: in1 slot(s+7)
//     c0..63 (h0(tau-1), wr tau-1 by L0; same-slot L1 rec write c64..127 disj)
//   L2 cur rec: in2 slot(s+4) c64..127 (wr tau-1) | L2 pre: in2 slot(s+5)
//     c0..63 (h1(tau-3), wr tau-1 by L1; same-slot L2 rec write c64..127 disj)
// All producer->consumer edges >=1 barrier; overwrite distance >=7 ticks.
// Guards: pre(tau) active <=> cur(tau+1) active (acc always prepared):
//   L0 cur tau<=999 / pre tau<=998; L1 cur 2..1001 / pre 1..1000;
//   L2 cur 4..1003 / pre 3..1002; ST write tau<=997.
// 896 thr = 14 waves: 0-3 L2, 4-7 L1, 8-11 L0, 12-13 stager.
#define TT 1000
#define FF 22
#define HH 64
#define BB 4
#define NBLK 256
#define S0 112
#define S1 144
#define SL0 (4 * S0)
#define SL1 (4 * S1)

typedef _Float16 half8 __attribute__((ext_vector_type(8)));
typedef float float4v __attribute__((ext_vector_type(4)));

__device__ __forceinline__ float sel4(const float4v a, int q) {
    float lo = (q & 2) ? a[2] : a[0];
    float hi = (q & 2) ? a[3] : a[1];
    return (q & 1) ? hi : lo;
}

// Fused LSTM gate math: 5 exp + 2 rcp (R13, verified absmax 2.44e-4).
__device__ __forceinline__ float gate_fused(const float z[4], float& c) {
    float e0 = __expf(-z[0]);
    float e1 = __expf(-z[1]);
    float e2 = __expf(2.0f * z[2]);
    float d1 = 1.0f + e1;
    float d2 = (1.0f + e0) * (1.0f + e2);
    float r  = __builtin_amdgcn_rcpf(d1 * d2);
    float f  = d2 * r;
    float ig = (e2 - 1.0f) * (d1 * r);
    float cc = __builtin_fmaf(f, c, ig);
    c = cc;
    float e3 = __expf(-z[3]);
    float e4 = __expf(2.0f * cc);
    float r2 = __builtin_amdgcn_rcpf((1.0f + e3) * (1.0f + e4));
    return (e4 - 1.0f) * r2;
}

// tick boundary: LDS release + barrier + compiler fence
#define SYNC() do { asm volatile("s_waitcnt lgkmcnt(0)" ::: "memory"); \
                    __builtin_amdgcn_s_barrier(); \
                    asm volatile("" ::: "memory"); } while (0)
#define SB()   __builtin_amdgcn_sched_barrier(0)

extern "C" __global__ void __launch_bounds__(896, 1)
lstm_fused(const float* __restrict__ x,
           const float* __restrict__ Wih0, const float* __restrict__ Whh0,
           const float* __restrict__ bih0, const float* __restrict__ bhh0,
           const float* __restrict__ Wih1, const float* __restrict__ Whh1,
           const float* __restrict__ bih1, const float* __restrict__ bhh1,
           const float* __restrict__ Wih2, const float* __restrict__ Whh2,
           const float* __restrict__ bih2, const float* __restrict__ bhh2,
           const float* __restrict__ w0, const float* __restrict__ b0,
           const float* __restrict__ w1, const float* __restrict__ b1,
           const float* __restrict__ w2, const float* __restrict__ b2,
           const float* __restrict__ w3, const float* __restrict__ b3,
           const float* __restrict__ g0, const float* __restrict__ be0,
           const float* __restrict__ m0, const float* __restrict__ v0,
           const float* __restrict__ g1, const float* __restrict__ be1,
           const float* __restrict__ m1, const float* __restrict__ v1,
           const float* __restrict__ g2, const float* __restrict__ be2,
           const float* __restrict__ m2, const float* __restrict__ v2,
           float* __restrict__ out)
{
    __shared__ __align__(16) _Float16 in0[8 * SL0];
    __shared__ __align__(16) _Float16 in1[8 * SL1];
    __shared__ __align__(16) _Float16 in2[8 * SL1];
    __shared__ float fcA[BB * 64];
    __shared__ float fcB[BB * 64];
    __shared__ float fcW[54 * 65];
    __shared__ float fcP[5 * 64];

    const int tid  = threadIdx.x;
    const int wv   = tid >> 6;      // 0..13
    const int role = wv >> 2;       // 0=L2, 1=L1, 2=L0, 3=stager
    const int w4   = wv & 3;
    const int l    = tid & 63;
    const int q    = l >> 4;
    const int l15  = l & 15;
    const int u    = 16 * w4 + l15;
    const int b    = q;
    const int n0   = blockIdx.x * BB;

    for (int i = tid; i < 8 * SL0; i += 896) in0[i] = (_Float16)0.0f;
    for (int i = tid; i < 8 * SL1; i += 896) in1[i] = (_Float16)0.0f;
    for (int i = tid; i < 8 * SL1; i += 896) in2[i] = (_Float16)0.0f;

    // ---- weight B-fragments: one unit-slice per wave ----
    half8 wf[4][4];
    float bv[4];
    if (role == 2) {                 // layer 0 (3 kt used)
#pragma unroll
        for (int g = 0; g < 4; ++g) {
            const int row = 64 * g + u;
#pragma unroll
            for (int kt = 0; kt < 3; ++kt) {
                half8 h{};
#pragma unroll
                for (int j = 0; j < 8; ++j) {
                    const int k = 32 * kt + 8 * q + j;
                    float val = 0.0f;
                    if (k < 32) { if (k < FF) val = Wih0[row * FF + k]; }
                    else        { val = Whh0[row * HH + (k - 32)]; }
                    h[j] = (_Float16)val;
                }
                wf[g][kt] = h;
            }
            wf[g][3] = half8{};
            bv[g] = bih0[row] + bhh0[row];
        }
    } else if (role < 2) {            // 0 -> layer 2, 1 -> layer 1
        const float* Wih = role ? Wih1 : Wih2;
        const float* Whh = role ? Whh1 : Whh2;
        const float* bih = role ? bih1 : bih2;
        const float* bhh = role ? bhh1 : bhh2;
#pragma unroll
        for (int g = 0; g < 4; ++g) {
            const int row = 64 * g + u;
#pragma unroll
            for (int kt = 0; kt < 4; ++kt) {
                half8 h{};
#pragma unroll
                for (int j = 0; j < 8; ++j) {
                    const int k = 32 * kt + 8 * q + j;
                    h[j] = (_Float16)((k < 64) ? Wih[row * HH + k] : Whh[row * HH + (k - 64)]);
                }
                wf[g][kt] = h;
            }
            bv[g] = bih[row] + bhh[row];
        }
    }

    // ---- x staging lanes: waves 12-13, 88 items ----
    const int  st  = tid - 768;
    const bool xok = (role == 3) && (st >= 0) && (st < BB * FF);
    const int  xb  = xok ? (st / FF) : 0;
    const int  xf  = xok ? (st - xb * FF) : 0;
    const float* xp = x + ((size_t)(n0 + xb) * FF + xf) * TT;

    __syncthreads();                 // zero-init visible

    // pre-stage x(0) -> slot 0, x(1) -> slot 1
    if (xok) {
        in0[0 * SL0 + xb * S0 + xf] = (_Float16)xp[0];
        in0[1 * SL0 + xb * S0 + xf] = (_Float16)xp[1];
    }
    float xA = xok ? xp[2] : 0.f;    // x(tau+2) to write at tick tau=0
    float xB = xok ? xp[3] : 0.f;    // depth-2 prefetch

    __syncthreads();                 // pre-staged x visible

    const int arow = (role == 2) ? ((l15 & 3) * S0 + q * 8) : ((l15 & 3) * S1 + q * 8);
    float c = 0.f;
    const float4v zz = {0.f, 0.f, 0.f, 0.f};
    float4v acc[4] = {zz, zz, zz, zz};

    // prologue: L0 issues fwd MFMAs for step 0 (x(0) pre-staged in slot 0)
    if (role == 2) {
        half8 f0 = *(const half8*)(in0 + 0 * SL0 + arow);
#pragma unroll
        for (int g = 0; g < 4; ++g)
            acc[g] = __builtin_amdgcn_mfma_f32_16x16x32_f16(f0, wf[g][0], zz, 0, 0, 0);
    }

    // ============ main loop: 126*8 = 1008 ticks, 1 barrier each ============
    for (int k = 0; k < 126; ++k) {
#pragma unroll
        for (int s = 0; s < 8; ++s) {
            const int tau = 8 * k + s;
            SYNC();

            if (role == 3) {         // ===== stager: write x(tau+2) =====
                if (tau <= TT - 3) {
                    if (xok) in0[((s + 2) & 7) * SL0 + xb * S0 + xf] = (_Float16)xA;
                    xA = xB;
                    if (xok) {
                        int tn = tau + 4; if (tn > TT - 1) tn = TT - 1;
                        xB = xp[tn];
                    }
                }
            } else if (role == 2) {  // ===== L0: cur t = tau =====
                const bool act  = (tau <= TT - 1);
                const bool actn = (tau <= TT - 2);
                half8 f0{};
                if (act) {
                    const _Float16* rd = in0 + s * SL0;
                    half8 r1 = *(const half8*)(rd + arow + 32);   // rec lo
                    half8 r2 = *(const half8*)(rd + arow + 64);   // rec hi
#pragma unroll
                    for (int g = 0; g < 4; ++g)
                        acc[g] = __builtin_amdgcn_mfma_f32_16x16x32_f16(r1, wf[g][1], acc[g], 0, 0, 0);
#pragma unroll
                    for (int g = 0; g < 4; ++g)
                        acc[g] = __builtin_amdgcn_mfma_f32_16x16x32_f16(r2, wf[g][2], acc[g], 0, 0, 0);
                }
                if (actn)            // pre-read x(tau+1) (hidden under gates)
                    f0 = *(const half8*)(in0 + ((s + 1) & 7) * SL0 + arow);
                if (act) {
                    float z[4];
#pragma unroll
                    for (int g = 0; g < 4; ++g) z[g] = sel4(acc[g], q) + bv[g];
                    float h = gate_fused(z, c);
                    _Float16 hf = (_Float16)h;
                    in0[((s + 1) & 7) * SL0 + b * S0 + 32 + u] = hf; // rec -> slot tau+1
                    in1[s * SL1 + b * S1 + u]                  = hf; // fwd -> slot tau
                }
                if (actn) {          // pre-ISSUE fwd MFMAs for step tau+1
#pragma unroll
                    for (int g = 0; g < 4; ++g)
                        acc[g] = __builtin_amdgcn_mfma_f32_16x16x32_f16(f0, wf[g][0], zz, 0, 0, 0);
                }
            } else if (role == 1) {  // ===== L1: cur t = tau-2 =====
                const bool act  = (tau >= 2) && (tau <= TT + 1);
                const bool actn = (tau >= 1) && (tau <= TT);
                half8 f0{}, f1{};
                if (act) {
                    const _Float16* rr = in1 + ((s + 6) & 7) * SL1;
                    half8 r2 = *(const half8*)(rr + arow + 64);   // rec lo
                    half8 r3 = *(const half8*)(rr + arow + 96);   // rec hi
#pragma unroll
                    for (int g = 0; g < 4; ++g)
                        acc[g] = __builtin_amdgcn_mfma_f32_16x16x32_f16(r2, wf[g][2], acc[g], 0, 0, 0);
#pragma unroll
                    for (int g = 0; g < 4; ++g)
                        acc[g] = __builtin_amdgcn_mfma_f32_16x16x32_f16(r3, wf[g][3], acc[g], 0, 0, 0);
                }
                if (actn) {          // pre-read h0(tau-1) fwd
                    const _Float16* rn = in1 + ((s + 7) & 7) * SL1;
                    f0 = *(const half8*)(rn + arow);
                    f1 = *(const half8*)(rn + arow + 32);
                }
                if (act) {
                    float z[4];
#pragma unroll
                    for (int g = 0; g < 4; ++g) z[g] = sel4(acc[g], q) + bv[g];
                    float h = gate_fused(z, c);
                    _Float16 hf = (_Float16)h;
                    in1[((s + 7) & 7) * SL1 + b * S1 + 64 + u] = hf; // rec -> slot (tau-1)&7
                    in2[((s + 6) & 7) * SL1 + b * S1 + u]      = hf; // fwd -> slot (tau-2)&7
                }
                if (actn) {          // pre-ISSUE fwd MFMAs for step tau-1
#pragma unroll
                    for (int g = 0; g < 4; ++g)
                        acc[g] = __builtin_amdgcn_mfma_f32_16x16x32_f16(f0, wf[g][0], zz, 0, 0, 0);
#pragma unroll
                    for (int g = 0; g < 4; ++g)
                        acc[g] = __builtin_amdgcn_mfma_f32_16x16x32_f16(f1, wf[g][1], acc[g], 0, 0, 0);
                }
            } else {                 // ===== L2: cur t = tau-4 =====
                const bool act  = (tau >= 4) && (tau <= TT + 3);
                const bool actn = (tau >= 3) && (tau <= TT + 2);
                half8 f0{}, f1{};
                if (act) {
                    const _Float16* rr = in2 + ((s + 4) & 7) * SL1;
                    half8 r2 = *(const half8*)(rr + arow + 64);   // rec lo
                    half8 r3 = *(const half8*)(rr + arow + 96);   // rec hi
#pragma unroll
                    for (int g = 0; g < 4; ++g)
                        acc[g] = __builtin_amdgcn_mfma_f32_16x16x32_f16(r2, wf[g][2], acc[g], 0, 0, 0);
#pragma unroll
                    for (int g = 0; g < 4; ++g)
                        acc[g] = __builtin_amdgcn_mfma_f32_16x16x32_f16(r3, wf[g][3], acc[g], 0, 0, 0);
                }
                if (actn) {          // pre-read h1(tau-3) fwd
                    const _Float16* rn = in2 + ((s + 5) & 7) * SL1;
                    f0 = *(const half8*)(rn + arow);
                    f1 = *(const half8*)(rn + arow + 32);
                }
                if (act) {
                    float z[4];
#pragma unroll
                    for (int g = 0; g < 4; ++g) z[g] = sel4(acc[g], q) + bv[g];
                    float h = gate_fused(z, c);
                    if (tau != TT + 3) {
                        in2[((s + 5) & 7) * SL1 + b * S1 + 64 + u] = (_Float16)h; // rec -> slot (tau-3)&7
                    } else {
                        fcA[b * 64 + u] = h;              // final h2(999), fp32
                    }
                }
                if (actn) {          // pre-ISSUE fwd MFMAs for step tau-3
#pragma unroll
                    for (int g = 0; g < 4; ++g)
                        acc[g] = __builtin_amdgcn_mfma_f32_16x16x32_f16(f0, wf[g][0], zz, 0, 0, 0);
#pragma unroll
                    for (int g = 0; g < 4; ++g)
                        acc[g] = __builtin_amdgcn_mfma_f32_16x16x32_f16(f1, wf[g][1], acc[g], 0, 0, 0);
                }
            }
            SB();                    // pin pre-issued MFMAs before the barrier
        }
    }

    __syncthreads();

    // ================= FC head (fp32) =================
    for (int i = tid; i < 54 * 64; i += 896) fcW[(i >> 6) * 65 + (i & 63)] = w0[i];
    for (int i = tid; i < 54; i += 896) {
        fcP[i] = b0[i]; fcP[64 + i] = g0[i]; fcP[128 + i] = be0[i];
        fcP[192 + i] = m0[i]; fcP[256 + i] = v0[i];
    }
    __syncthreads();
    for (int idx = tid; idx < BB * 54; idx += 896) {
        const int bb = idx / 54, j = idx - bb * 54;
        float s = fcP[j];
        for (int k = 0; k < 64; ++k) s += fcW[j * 65 + k] * fcA[bb * 64 + k];
        s = (s - fcP[192 + j]) * rsqrtf(fcP[256 + j] + 1e-5f) * fcP[64 + j] + fcP[128 + j];
        fcB[bb * 64 + j] = fmaxf(s, 0.0f);
    }
    __syncthreads();

    for (int i = tid; i < 44 * 54; i += 896) fcW[(i / 54) * 55 + (i % 54)] = w1[i];
    for (int i = tid; i < 44; i += 896) {
        fcP[i] = b1[i]; fcP[64 + i] = g1[i]; fcP[128 + i] = be1[i];
        fcP[192 + i] = m1[i]; fcP[256 + i] = v1[i];
    }
    __syncthreads();
    for (int idx = tid; idx < BB * 44; idx += 896) {
        const int bb = idx / 44, j = idx - bb * 44;
        float s = fcP[j];
        for (int k = 0; k < 54; ++k) s += fcW[j * 55 + k] * fcB[bb * 64 + k];
        s = (s - fcP[192 + j]) * rsqrtf(fcP[256 + j] + 1e-5f) * fcP[64 + j] + fcP[128 + j];
        fcA[bb * 64 + j] = fmaxf(s, 0.0f);
    }
    __syncthreads();

    for (int i = tid; i < 24 * 44; i += 896) fcW[(i / 44) * 45 + (i % 44)] = w2[i];
    for (int i = tid; i < 24; i += 896) {
        fcP[i] = b2[i]; fcP[64 + i] = g2[i]; fcP[128 + i] = be2[i];
        fcP[192 + i] = m2[i]; fcP[256 + i] = v2[i];
    }
    __syncthreads();
    for (int idx = tid; idx < BB * 24; idx += 896) {
        const int bb = idx / 24, j = idx - bb * 24;
        float s = fcP[j];
        for (int k = 0; k < 44; ++k) s += fcW[j * 45 + k] * fcA[bb * 64 + k];
        s = (s - fcP[192 + j]) * rsqrtf(fcP[256 + j] + 1e-5f) * fcP[64 + j] + fcP[128 + j];
        fcB[bb * 64 + j] = fmaxf(s, 0.0f);
    }
    __syncthreads();

    for (int i = tid; i < 4 * 24; i += 896) fcW[(i / 24) * 25 + (i % 24)] = w3[i];
    for (int i = tid; i < 4; i += 896) fcP[i] = b3[i];
    __syncthreads();
    for (int idx = tid; idx < BB * 4; idx += 896) {
        const int bb = idx / 4, j = idx - bb * 4;
        float s = fcP[j];
        for (int k = 0; k < 24; ++k) s += fcW[j * 25 + k] * fcB[bb * 64 + k];
        out[(size_t)(n0 + bb) * 4 + j] = s;
    }
}

extern "C" void kernel_launch(void* const* d_in, const int* in_sizes, int n_in,
                              void* d_out, int out_size, void* d_ws, size_t ws_size,
                              hipStream_t stream) {
    const float* p[33];
    for (int i = 0; i < 33; ++i) p[i] = (const float*)d_in[i];
    lstm_fused<<<NBLK, 896, 0, stream>>>(
        p[0],
        p[1], p[2], p[3], p[4],
        p[5], p[6], p[7], p[8],
        p[9], p[10], p[11], p[12],
        p[13], p[14], p[15], p[16], p[17], p[18], p[19], p[20],
        p[21], p[22], p[23], p[24],
        p[25], p[26], p[27], p[28],
        p[29], p[30], p[31], p[32],
        (float*)d_out);
}